// Round 8
// baseline (48.331 us; speedup 1.0000x reference)
//
#include <hip/hip_runtime.h>
#include <math.h>

#define B_  16
#define T_  16
#define N_  256
#define D_  384
#define Q_  384
#define K_  16
#define BT_ (B_ * T_)

// R8: (a) qproj re-written as bt-tiled batched GEMV (96 blocks x 512 thr,
// 8 bt x 128 d outputs per block) -> W_in L2 traffic drops 147MB -> ~19MB;
// (b) scores phase pipelined 3-deep (18 float4 in flight, ~120 VGPR).

#define QP_DT 128   // d-cols per block
#define QP_BT 8     // bt rows per block

// ---------------------------------------------------------------------------
// K1: qp[bt0..+8, d0..+128] = queries[bt0..+8] @ W_in[:, d0..+128] + b_in
// grid (3 d-tiles, 32 bt-tiles) x 512 thr. Thread: (r=tid>>7, dcol=tid&127)
// owns outputs (bt0+r*2+{0,1}, d0+dcol).
// ---------------------------------------------------------------------------
__global__ __launch_bounds__(512)
void qproj_kernel(const float* __restrict__ queries,  // [BT_, Q_]
                  const float* __restrict__ W_in,     // [Q_, D_]
                  const float* __restrict__ b_in,     // [D_]
                  float* __restrict__ qp)             // [BT_, D_]
{
    const int d0  = blockIdx.x * QP_DT;
    const int bt0 = blockIdx.y * QP_BT;
    const int tid = threadIdx.x;            // 0..511

    __shared__ __align__(16) float s_q[QP_BT][Q_];   // 12 KB

    // stage 8x384 floats = 768 float4; 512 threads -> 1.5 each
    {
        const float4* src = reinterpret_cast<const float4*>(queries + (size_t)bt0 * Q_);
        float4* dst = reinterpret_cast<float4*>(&s_q[0][0]);
        dst[tid] = src[tid];
        if (tid < 256) dst[tid + 512] = src[tid + 512];
    }
    __syncthreads();

    const int dcol = tid & 127;
    const int r    = tid >> 7;              // 0..3
    const int d    = d0 + dcol;
    const int bta  = r * 2;
    const int btb  = r * 2 + 1;

    float acc0 = 0.f, acc1 = 0.f;
    #pragma unroll 4
    for (int q = 0; q < Q_; q += 4) {
        const float w0 = W_in[(size_t)(q + 0) * D_ + d];
        const float w1 = W_in[(size_t)(q + 1) * D_ + d];
        const float w2 = W_in[(size_t)(q + 2) * D_ + d];
        const float w3 = W_in[(size_t)(q + 3) * D_ + d];
        const float4 qa = *reinterpret_cast<const float4*>(&s_q[bta][q]);
        const float4 qb = *reinterpret_cast<const float4*>(&s_q[btb][q]);
        acc0 += qa.x * w0 + qa.y * w1 + qa.z * w2 + qa.w * w3;
        acc1 += qb.x * w0 + qb.y * w1 + qb.z * w2 + qb.w * w3;
    }
    const float bi = b_in[d];
    qp[(size_t)(bt0 + bta) * D_ + d] = acc0 + bi;
    qp[(size_t)(bt0 + btb) * D_ + d] = acc1 + bi;
}

// ---------------------------------------------------------------------------
// K2: per (b,t): scores -> softmax -> exact top-K -> weighted sum -> outproj.
// 256 blocks x 1024 threads. Scores: 3-deep row pipeline, qp in registers.
// ---------------------------------------------------------------------------
__global__ __launch_bounds__(1024, 4)
void fused_kernel(const float* __restrict__ patch,   // [BT_, N_, D_]
                  const float* __restrict__ qp,      // [BT_, D_]
                  const float* __restrict__ W_out,   // [D_, Q_]
                  const float* __restrict__ b_out,   // [Q_]
                  float* __restrict__ out)           // [BT_, Q_]
{
    const int bt   = blockIdx.x;
    const int tid  = threadIdx.x;       // 0..1023
    const int lane = tid & 63;
    const int wave = tid >> 6;          // 0..15

    __shared__ __align__(16) float s_qp[D_];
    __shared__ float s_sc[N_];
    __shared__ int   s_cnt4[N_][4];
    __shared__ float s_red[4];
    __shared__ float s_red2[4][2];
    __shared__ float s_w[K_];
    __shared__ int   s_ix[K_];
    __shared__ float s_part[2 * D_];
    __shared__ float s_od[D_];

    const float* __restrict__ ptile = patch + (size_t)bt * N_ * D_;

    if (tid < D_) s_qp[tid] = qp[(size_t)bt * D_ + tid];
    __syncthreads();

    // ---- scores: 64 groups x 4 rows; 3-deep load pipeline ----
    {
        const int g  = lane >> 4;       // 0..3
        const int sl = lane & 15;
        const int n0 = wave * 4 + g;    // rows n0 + {0,64,128,192}
        const float4* s_qp4 = reinterpret_cast<const float4*>(s_qp);

        float4 qv[6];
        #pragma unroll
        for (int c = 0; c < 6; ++c) qv[c] = s_qp4[c * 16 + sl];

        float4 A[6], Bu[6], C[6];

#define LOADROW(dst, it) {                                                     \
        const float* pr = ptile + (size_t)(n0 + (it) * 64) * D_;               \
        _Pragma("unroll")                                                      \
        for (int c = 0; c < 6; ++c)                                            \
            dst[c] = *reinterpret_cast<const float4*>(pr + c * 64 + 4 * sl); }

#define DOTSTORE(src, it) {                                                    \
        float p = 0.f;                                                         \
        _Pragma("unroll")                                                      \
        for (int c = 0; c < 6; ++c)                                            \
            p += src[c].x * qv[c].x + src[c].y * qv[c].y                       \
               + src[c].z * qv[c].z + src[c].w * qv[c].w;                      \
        _Pragma("unroll")                                                      \
        for (int off = 8; off; off >>= 1) p += __shfl_xor(p, off, 16);         \
        if (sl == 0) s_sc[n0 + (it) * 64] = p; }

        LOADROW(A, 0)
        LOADROW(Bu, 1)
        LOADROW(C, 2)
        DOTSTORE(A, 0)
        LOADROW(A, 3)
        DOTSTORE(Bu, 1)
        DOTSTORE(C, 2)
        DOTSTORE(A, 3)
#undef LOADROW
#undef DOTSTORE
    }
    __syncthreads();

    // ---- block max (waves 0-3) + rank partial counts (all 1024 threads) ----
    if (tid < N_) {
        float v = s_sc[tid];
        #pragma unroll
        for (int off = 32; off; off >>= 1) v = fmaxf(v, __shfl_xor(v, off));
        if (lane == 0) s_red[wave] = v;
    }
    {
        const int i   = tid >> 2;       // 0..255
        const int sub = tid & 3;        // j in [sub*64, sub*64+64)
        const float si = s_sc[i];
        int c = 0;
        #pragma unroll 8
        for (int j = sub * 64; j < sub * 64 + 64; ++j) {
            const float sj = s_sc[j];
            c += (int)(sj > si) | ((int)(sj == si) & (int)(j < i));
        }
        s_cnt4[i][sub] = c;
    }
    __syncthreads();

    // ---- e, Z, SK (threads < 256) ----
    float e = 0.f;
    int   cnt = N_;
    if (tid < N_) {
        const float mx = fmaxf(fmaxf(s_red[0], s_red[1]), fmaxf(s_red[2], s_red[3]));
        cnt = s_cnt4[tid][0] + s_cnt4[tid][1] + s_cnt4[tid][2] + s_cnt4[tid][3];
        e = __expf(s_sc[tid] - mx);

        float z  = e;
        float sk = (cnt < K_) ? e : 0.f;
        #pragma unroll
        for (int off = 32; off; off >>= 1) {
            z  += __shfl_xor(z, off);
            sk += __shfl_xor(sk, off);
        }
        if (lane == 0) { s_red2[wave][0] = z; s_red2[wave][1] = sk; }
    }
    __syncthreads();

    // weight_i = softmax_i / (sum_topk + EPS) = e_i / (SK + EPS*Z)
    {
        const float Z  = s_red2[0][0] + s_red2[1][0] + s_red2[2][0] + s_red2[3][0];
        const float SK = s_red2[0][1] + s_red2[1][1] + s_red2[2][1] + s_red2[3][1];
        const float inv = 1.f / (SK + 1e-8f * Z);
        if (tid < N_ && cnt < K_) {
            s_ix[cnt] = tid;
            s_w[cnt]  = e * inv;
        }
    }
    __syncthreads();

    // ---- weighted sum over K rows: 768 thr, 2-way split over j ----
    if (tid < 2 * D_) {
        const int half = tid >= D_;
        const int d    = tid - half * D_;
        const int j0   = half * (K_ / 2);
        float acc = 0.f;
        #pragma unroll
        for (int j = j0; j < j0 + K_ / 2; ++j)
            acc += s_w[j] * ptile[(size_t)s_ix[j] * D_ + d];
        s_part[tid] = acc;
    }
    __syncthreads();
    if (tid < D_) s_od[tid] = s_part[tid] + s_part[tid + D_];
    __syncthreads();

    // ---- out-proj: 768 thr, 2-way split-K, 4 accumulator chains ----
    if (tid < 2 * Q_) {
        const int half = tid >= Q_;
        const int q    = tid - half * Q_;
        const int d0   = half * (D_ / 2);
        float a0 = 0.f, a1 = 0.f, a2 = 0.f, a3 = 0.f;
        #pragma unroll 4
        for (int d = d0; d < d0 + D_ / 2; d += 4) {
            a0 += s_od[d]     * W_out[(size_t)(d)     * Q_ + q];
            a1 += s_od[d + 1] * W_out[(size_t)(d + 1) * Q_ + q];
            a2 += s_od[d + 2] * W_out[(size_t)(d + 2) * Q_ + q];
            a3 += s_od[d + 3] * W_out[(size_t)(d + 3) * Q_ + q];
        }
        s_part[tid] = (a0 + a1) + (a2 + a3);
    }
    __syncthreads();
    if (tid < Q_)
        out[(size_t)bt * Q_ + tid] = s_part[tid] + s_part[tid + Q_] + b_out[tid];
}

extern "C" void kernel_launch(void* const* d_in, const int* in_sizes, int n_in,
                              void* d_out, int out_size, void* d_ws, size_t ws_size,
                              hipStream_t stream) {
    const float* queries = (const float*)d_in[0];
    const float* patch   = (const float*)d_in[1];
    const float* W_in    = (const float*)d_in[2];
    const float* b_in    = (const float*)d_in[3];
    const float* W_out   = (const float*)d_in[4];
    const float* b_out   = (const float*)d_in[5];
    float* out = (float*)d_out;

    float* qp = (float*)d_ws;                 // [BT_, D_]

    qproj_kernel<<<dim3(D_ / QP_DT, BT_ / QP_BT), dim3(512), 0, stream>>>(
        queries, W_in, b_in, qp);
    fused_kernel<<<dim3(BT_), dim3(1024), 0, stream>>>(
        patch, qp, W_out, b_out, out);
}

// Round 9
// 35.952 us; speedup vs baseline: 1.3443x; 1.3443x over previous
//
#include <hip/hip_runtime.h>
#include <math.h>

#define B_  16
#define T_  16
#define N_  256
#define D_  384
#define Q_  384
#define K_  16
#define BT_ (B_ * T_)

// R9: single fused kernel (node algebra: each extra node ~+2-4us, and a
// separate qproj kernel reads the same 147MB of W_in L2 traffic anyway).
// Key trick: scores-phase patch loads don't depend on q_proj, so each wave
// issues its first 2 rows of patch loads BEFORE the qproj GEMV; the prefetch
// streams from HBM/L3 while qproj does its L2-bound W_in GEMV. R7's 2-deep
// pipeline finishes the remaining rows. R8 lesson: stay under 128 VGPR.
__global__ __launch_bounds__(1024, 4)
void fused_kernel(const float* __restrict__ queries,  // [BT_, Q_]
                  const float* __restrict__ patch,    // [BT_, N_, D_]
                  const float* __restrict__ W_in,     // [Q_, D_]
                  const float* __restrict__ b_in,     // [D_]
                  const float* __restrict__ W_out,    // [D_, Q_]
                  const float* __restrict__ b_out,    // [Q_]
                  float* __restrict__ out)            // [BT_, Q_]
{
    const int bt   = blockIdx.x;
    const int tid  = threadIdx.x;       // 0..1023
    const int lane = tid & 63;
    const int wave = tid >> 6;          // 0..15

    __shared__ __align__(16) float s_q[Q_];
    __shared__ __align__(16) float s_qp[D_];
    __shared__ float s_sc[N_];
    __shared__ int   s_cnt4[N_][4];
    __shared__ float s_red[4];
    __shared__ float s_red2[4][2];
    __shared__ float s_w[K_];
    __shared__ int   s_ix[K_];
    __shared__ float s_part[2 * D_];
    __shared__ float s_od[D_];

    const float* __restrict__ ptile = patch + (size_t)bt * N_ * D_;

    // ---- stage query row, then barrier (only the tiny queries load drains) --
    if (tid < Q_) s_q[tid] = queries[(size_t)bt * Q_ + tid];
    __syncthreads();

    const int g  = lane >> 4;           // 0..3
    const int sl = lane & 15;
    const int n0 = wave * 4 + g;        // rows n0 + {0,64,128,192}

    float4 A[6], Bu[6];

#define LOADROW(dst, it) {                                                     \
        const float* pr = ptile + (size_t)(n0 + (it) * 64) * D_;               \
        _Pragma("unroll")                                                      \
        for (int c = 0; c < 6; ++c)                                            \
            dst[c] = *reinterpret_cast<const float4*>(pr + c * 64 + 4 * sl); }

#define DOTSTORE(src, it) {                                                    \
        float p = 0.f;                                                         \
        _Pragma("unroll")                                                      \
        for (int c = 0; c < 6; ++c)                                            \
            p += src[c].x * qv[c].x + src[c].y * qv[c].y                       \
               + src[c].z * qv[c].z + src[c].w * qv[c].w;                      \
        _Pragma("unroll")                                                      \
        for (int off = 8; off; off >>= 1) p += __shfl_xor(p, off, 16);         \
        if (sl == 0) s_sc[n0 + (it) * 64] = p; }

    // ---- issue patch prefetch for rows 0,1 (independent of q_proj) ----
    LOADROW(A, 0)
    LOADROW(Bu, 1)
    __builtin_amdgcn_sched_barrier(0);  // pin prefetch issue before qproj

    // ---- q_proj while prefetch streams: 768 thr, 2-way split-K, 4 chains ----
    if (tid < 2 * D_) {
        const int half = tid >= D_;
        const int d    = tid - half * D_;
        const int q0   = half * (Q_ / 2);
        float a0 = 0.f, a1 = 0.f, a2 = 0.f, a3 = 0.f;
        #pragma unroll 4
        for (int q = q0; q < q0 + Q_ / 2; q += 4) {
            a0 += s_q[q]     * W_in[(size_t)(q)     * D_ + d];
            a1 += s_q[q + 1] * W_in[(size_t)(q + 1) * D_ + d];
            a2 += s_q[q + 2] * W_in[(size_t)(q + 2) * D_ + d];
            a3 += s_q[q + 3] * W_in[(size_t)(q + 3) * D_ + d];
        }
        s_part[tid] = (a0 + a1) + (a2 + a3);
    }
    __syncthreads();
    if (tid < D_) s_qp[tid] = s_part[tid] + s_part[tid + D_] + b_in[tid];
    __syncthreads();   // drains vmcnt too — prefetch has arrived by now

    // ---- scores: rows 0,1 from prefetch; rows 2,3 pipelined ----
    {
        const float4* s_qp4 = reinterpret_cast<const float4*>(s_qp);
        float4 qv[6];
        #pragma unroll
        for (int c = 0; c < 6; ++c) qv[c] = s_qp4[c * 16 + sl];

        DOTSTORE(A, 0)
        LOADROW(A, 2)
        DOTSTORE(Bu, 1)
        LOADROW(Bu, 3)
        DOTSTORE(A, 2)
        DOTSTORE(Bu, 3)
    }
#undef LOADROW
#undef DOTSTORE
    __syncthreads();

    // ---- block max (waves 0-3) + rank partial counts (all 1024 threads) ----
    if (tid < N_) {
        float v = s_sc[tid];
        #pragma unroll
        for (int off = 32; off; off >>= 1) v = fmaxf(v, __shfl_xor(v, off));
        if (lane == 0) s_red[wave] = v;
    }
    {
        const int i   = tid >> 2;       // 0..255
        const int sub = tid & 3;        // j in [sub*64, sub*64+64)
        const float si = s_sc[i];
        int c = 0;
        #pragma unroll 8
        for (int j = sub * 64; j < sub * 64 + 64; ++j) {
            const float sj = s_sc[j];
            c += (int)(sj > si) | ((int)(sj == si) & (int)(j < i));
        }
        s_cnt4[i][sub] = c;
    }
    __syncthreads();

    // ---- e, Z, SK (threads < 256) ----
    float e = 0.f;
    int   cnt = N_;
    if (tid < N_) {
        const float mx = fmaxf(fmaxf(s_red[0], s_red[1]), fmaxf(s_red[2], s_red[3]));
        cnt = s_cnt4[tid][0] + s_cnt4[tid][1] + s_cnt4[tid][2] + s_cnt4[tid][3];
        e = __expf(s_sc[tid] - mx);

        float z  = e;
        float sk = (cnt < K_) ? e : 0.f;
        #pragma unroll
        for (int off = 32; off; off >>= 1) {
            z  += __shfl_xor(z, off);
            sk += __shfl_xor(sk, off);
        }
        if (lane == 0) { s_red2[wave][0] = z; s_red2[wave][1] = sk; }
    }
    __syncthreads();

    // weight_i = softmax_i / (sum_topk + EPS) = e_i / (SK + EPS*Z)
    {
        const float Z  = s_red2[0][0] + s_red2[1][0] + s_red2[2][0] + s_red2[3][0];
        const float SK = s_red2[0][1] + s_red2[1][1] + s_red2[2][1] + s_red2[3][1];
        const float inv = 1.f / (SK + 1e-8f * Z);
        if (tid < N_ && cnt < K_) {
            s_ix[cnt] = tid;
            s_w[cnt]  = e * inv;
        }
    }
    __syncthreads();

    // ---- weighted sum over K rows: 768 thr, 2-way split over j ----
    if (tid < 2 * D_) {
        const int half = tid >= D_;
        const int d    = tid - half * D_;
        const int j0   = half * (K_ / 2);
        float acc = 0.f;
        #pragma unroll
        for (int j = j0; j < j0 + K_ / 2; ++j)
            acc += s_w[j] * ptile[(size_t)s_ix[j] * D_ + d];
        s_part[tid] = acc;
    }
    __syncthreads();
    if (tid < D_) s_od[tid] = s_part[tid] + s_part[tid + D_];
    __syncthreads();

    // ---- out-proj: 768 thr, 2-way split-K, 4 accumulator chains ----
    if (tid < 2 * Q_) {
        const int half = tid >= Q_;
        const int q    = tid - half * Q_;
        const int d0   = half * (D_ / 2);
        float a0 = 0.f, a1 = 0.f, a2 = 0.f, a3 = 0.f;
        #pragma unroll 4
        for (int d = d0; d < d0 + D_ / 2; d += 4) {
            a0 += s_od[d]     * W_out[(size_t)(d)     * Q_ + q];
            a1 += s_od[d + 1] * W_out[(size_t)(d + 1) * Q_ + q];
            a2 += s_od[d + 2] * W_out[(size_t)(d + 2) * Q_ + q];
            a3 += s_od[d + 3] * W_out[(size_t)(d + 3) * Q_ + q];
        }
        s_part[tid] = (a0 + a1) + (a2 + a3);
    }
    __syncthreads();
    if (tid < Q_)
        out[(size_t)bt * Q_ + tid] = s_part[tid] + s_part[tid + Q_] + b_out[tid];
}

extern "C" void kernel_launch(void* const* d_in, const int* in_sizes, int n_in,
                              void* d_out, int out_size, void* d_ws, size_t ws_size,
                              hipStream_t stream) {
    const float* queries = (const float*)d_in[0];
    const float* patch   = (const float*)d_in[1];
    const float* W_in    = (const float*)d_in[2];
    const float* b_in    = (const float*)d_in[3];
    const float* W_out   = (const float*)d_in[4];
    const float* b_out   = (const float*)d_in[5];
    float* out = (float*)d_out;

    fused_kernel<<<dim3(BT_), dim3(1024), 0, stream>>>(
        queries, patch, W_in, b_in, W_out, b_out, out);
}

// Round 10
// 35.669 us; speedup vs baseline: 1.3550x; 1.0079x over previous
//
#include <hip/hip_runtime.h>
#include <math.h>

#define B_  16
#define T_  16
#define N_  256
#define D_  384
#define Q_  384
#define K_  16
#define BT_ (B_ * T_)

// R10: single fused kernel (R9 structure) with three fixes:
//  1. qproj/outproj GEMVs use float4 W loads + 8-way split-K (768 thr:
//     s=tid/96 owns 48 k-steps, g=tid%96 owns 4 consecutive outputs).
//  2. rank-count reads s_sc as rotated float4 (2-way conflict = free,
//     was 4-way = 786K conflict cycles in R9).
//  3. s_cnt4 combined via int4 read.
__global__ __launch_bounds__(1024, 4)
void fused_kernel(const float* __restrict__ queries,  // [BT_, Q_]
                  const float* __restrict__ patch,    // [BT_, N_, D_]
                  const float* __restrict__ W_in,     // [Q_, D_]
                  const float* __restrict__ b_in,     // [D_]
                  const float* __restrict__ W_out,    // [D_, Q_]
                  const float* __restrict__ b_out,    // [Q_]
                  float* __restrict__ out)            // [BT_, Q_]
{
    const int bt   = blockIdx.x;
    const int tid  = threadIdx.x;       // 0..1023
    const int lane = tid & 63;
    const int wave = tid >> 6;          // 0..15

    __shared__ __align__(16) float s_q[Q_];
    __shared__ __align__(16) float s_qp[D_];
    __shared__ __align__(16) float s_sc[N_];
    __shared__ __align__(16) int   s_cnt4[N_][4];
    __shared__ float s_red[4];
    __shared__ float s_red2[4][2];
    __shared__ float s_w[K_];
    __shared__ int   s_ix[K_];
    __shared__ __align__(16) float s_p8[8][D_];   // split-K partials (reused)
    __shared__ __align__(16) float s_od[D_];

    const float* __restrict__ ptile = patch + (size_t)bt * N_ * D_;
    float* s_flat = &s_p8[0][0];

    // ---- stage query row ----
    if (tid < Q_) s_q[tid] = queries[(size_t)bt * Q_ + tid];
    __syncthreads();

    const int g16 = lane >> 4;          // 0..3
    const int sl  = lane & 15;
    const int n0  = wave * 4 + g16;     // rows n0 + {0,64,128,192}

    float4 A[6], Bu[6];

#define LOADROW(dst, it) {                                                     \
        const float* pr = ptile + (size_t)(n0 + (it) * 64) * D_;               \
        _Pragma("unroll")                                                      \
        for (int c = 0; c < 6; ++c)                                            \
            dst[c] = *reinterpret_cast<const float4*>(pr + c * 64 + 4 * sl); }

#define DOTSTORE(src, it) {                                                    \
        float p = 0.f;                                                         \
        _Pragma("unroll")                                                      \
        for (int c = 0; c < 6; ++c)                                            \
            p += src[c].x * qv[c].x + src[c].y * qv[c].y                       \
               + src[c].z * qv[c].z + src[c].w * qv[c].w;                      \
        _Pragma("unroll")                                                      \
        for (int off = 8; off; off >>= 1) p += __shfl_xor(p, off, 16);         \
        if (sl == 0) s_sc[n0 + (it) * 64] = p; }

    // ---- issue patch prefetch rows 0,1 (independent of q_proj) ----
    LOADROW(A, 0)
    LOADROW(Bu, 1)
    __builtin_amdgcn_sched_barrier(0);  // pin prefetch issue before qproj

    // ---- q_proj while prefetch streams: 768 thr, 8-way split-K, float4 W ----
    if (tid < 768) {
        const int s = tid / 96;         // k-split 0..7 -> q in [s*48, s*48+48)
        const int g = tid % 96;         // output cols 4g..4g+3
        float4 acc = {0.f, 0.f, 0.f, 0.f};
        const float* wp = W_in + (size_t)(s * 48) * D_ + 4 * g;
        #pragma unroll 4
        for (int qq = 0; qq < 48; ++qq) {
            const float4 w = *reinterpret_cast<const float4*>(wp + (size_t)qq * D_);
            const float qs = s_q[s * 48 + qq];
            acc.x += qs * w.x; acc.y += qs * w.y;
            acc.z += qs * w.z; acc.w += qs * w.w;
        }
        *reinterpret_cast<float4*>(&s_p8[s][4 * g]) = acc;
    }
    __syncthreads();
    if (tid < D_) {
        float v = b_in[tid];
        #pragma unroll
        for (int s = 0; s < 8; ++s) v += s_p8[s][tid];
        s_qp[tid] = v;
    }
    __syncthreads();   // prefetch has arrived under qproj

    // ---- scores: rows 0,1 from prefetch; rows 2,3 pipelined ----
    {
        const float4* s_qp4 = reinterpret_cast<const float4*>(s_qp);
        float4 qv[6];
        #pragma unroll
        for (int c = 0; c < 6; ++c) qv[c] = s_qp4[c * 16 + sl];

        DOTSTORE(A, 0)
        LOADROW(A, 2)
        DOTSTORE(Bu, 1)
        LOADROW(Bu, 3)
        DOTSTORE(A, 2)
        DOTSTORE(Bu, 3)
    }
#undef LOADROW
#undef DOTSTORE
    __syncthreads();

    // ---- block max (waves 0-3) + rank counts (rotated float4, 2-way) ----
    if (tid < N_) {
        float v = s_sc[tid];
        #pragma unroll
        for (int off = 32; off; off >>= 1) v = fmaxf(v, __shfl_xor(v, off));
        if (lane == 0) s_red[wave] = v;
    }
    {
        const int i   = tid >> 2;       // 0..255
        const int sub = tid & 3;        // chunk [sub*64, sub*64+64)
        const float si = s_sc[i];
        const float4* s_sc4 = reinterpret_cast<const float4*>(s_sc);
        int c = 0;
        #pragma unroll
        for (int jj = 0; jj < 16; ++jj) {
            const int jr = (jj + sub * 4) & 15;          // rotate start
            const float4 v = s_sc4[sub * 16 + jr];
            const int j0 = sub * 64 + jr * 4;
            c += (int)(v.x > si) | ((int)(v.x == si) & (int)((j0 + 0) < i));
            c += (int)(v.y > si) | ((int)(v.y == si) & (int)((j0 + 1) < i));
            c += (int)(v.z > si) | ((int)(v.z == si) & (int)((j0 + 2) < i));
            c += (int)(v.w > si) | ((int)(v.w == si) & (int)((j0 + 3) < i));
        }
        s_cnt4[i][sub] = c;
    }
    __syncthreads();

    // ---- e, Z, SK (threads < 256) ----
    float e = 0.f;
    int   cnt = N_;
    if (tid < N_) {
        const float mx = fmaxf(fmaxf(s_red[0], s_red[1]), fmaxf(s_red[2], s_red[3]));
        const int4 c4 = reinterpret_cast<const int4*>(s_cnt4)[tid];
        cnt = c4.x + c4.y + c4.z + c4.w;
        e = __expf(s_sc[tid] - mx);

        float z  = e;
        float sk = (cnt < K_) ? e : 0.f;
        #pragma unroll
        for (int off = 32; off; off >>= 1) {
            z  += __shfl_xor(z, off);
            sk += __shfl_xor(sk, off);
        }
        if (lane == 0) { s_red2[wave][0] = z; s_red2[wave][1] = sk; }
    }
    __syncthreads();

    // weight_i = softmax_i / (sum_topk + EPS) = e_i / (SK + EPS*Z)
    {
        const float Z  = s_red2[0][0] + s_red2[1][0] + s_red2[2][0] + s_red2[3][0];
        const float SK = s_red2[0][1] + s_red2[1][1] + s_red2[2][1] + s_red2[3][1];
        const float inv = 1.f / (SK + 1e-8f * Z);
        if (tid < N_ && cnt < K_) {
            s_ix[cnt] = tid;
            s_w[cnt]  = e * inv;
        }
    }
    __syncthreads();

    // ---- weighted sum over K rows: 768 thr, 2-way split over j ----
    if (tid < 2 * D_) {
        const int half = tid >= D_;
        const int d    = tid - half * D_;
        const int j0   = half * (K_ / 2);
        float acc = 0.f;
        #pragma unroll
        for (int j = j0; j < j0 + K_ / 2; ++j)
            acc += s_w[j] * ptile[(size_t)s_ix[j] * D_ + d];
        s_flat[tid] = acc;
    }
    __syncthreads();
    if (tid < D_) s_od[tid] = s_flat[tid] + s_flat[tid + D_];
    __syncthreads();

    // ---- out-proj: 768 thr, 8-way split-K, float4 W loads ----
    if (tid < 768) {
        const int s = tid / 96;         // k-split: d in [s*48, s*48+48)
        const int g = tid % 96;         // output cols 4g..4g+3
        float4 acc = {0.f, 0.f, 0.f, 0.f};
        const float* wp = W_out + (size_t)(s * 48) * Q_ + 4 * g;
        #pragma unroll 4
        for (int dd = 0; dd < 48; ++dd) {
            const float4 w = *reinterpret_cast<const float4*>(wp + (size_t)dd * Q_);
            const float ov = s_od[s * 48 + dd];
            acc.x += ov * w.x; acc.y += ov * w.y;
            acc.z += ov * w.z; acc.w += ov * w.w;
        }
        *reinterpret_cast<float4*>(&s_p8[s][4 * g]) = acc;
    }
    __syncthreads();
    if (tid < Q_) {
        float v = b_out[tid];
        #pragma unroll
        for (int s = 0; s < 8; ++s) v += s_p8[s][tid];
        out[(size_t)bt * Q_ + tid] = v;
    }
}

extern "C" void kernel_launch(void* const* d_in, const int* in_sizes, int n_in,
                              void* d_out, int out_size, void* d_ws, size_t ws_size,
                              hipStream_t stream) {
    const float* queries = (const float*)d_in[0];
    const float* patch   = (const float*)d_in[1];
    const float* W_in    = (const float*)d_in[2];
    const float* b_in    = (const float*)d_in[3];
    const float* W_out   = (const float*)d_in[4];
    const float* b_out   = (const float*)d_in[5];
    float* out = (float*)d_out;

    fused_kernel<<<dim3(BT_), dim3(1024), 0, stream>>>(
        queries, patch, W_in, b_in, W_out, b_out, out);
}